// Round 1
// baseline (4129.145 us; speedup 1.0000x reference)
//
#include <hip/hip_runtime.h>
#include <math.h>

#define NPG    1024
#define KNN    20
#define NGRAPH 64
#define NTOT   (NGRAPH * NPG)   // 65536
#define HD     16

// ---------------------------------------------------------------------------
// helpers
// ---------------------------------------------------------------------------
__device__ __forceinline__ float silu_f(float x) {
    float s = 1.0f / (1.0f + __expf(-x));
    return x * s;
}

// d2 computed with numpy's association order, no FMA contraction, so both
// knn passes (and the host reference) agree on boundary comparisons.
__device__ __forceinline__ float d2_exact(float xi, float yi, float zi, float sqi,
                                          float xj, float yj, float zj, float sqj) {
    float dot = __fadd_rn(__fadd_rn(__fmul_rn(xi, xj), __fmul_rn(yi, yj)),
                          __fmul_rn(zi, zj));
    return __fsub_rn(__fadd_rn(sqi, sqj), __fmul_rn(2.0f, dot));
}

// ---------------------------------------------------------------------------
// KNN: one thread per node; 4 blocks per graph; graph positions in LDS.
// Pass 1: top-20 smallest d2 VALUES via med3 insertion chain (cheap body).
// Pass 2: emit indices with d2 < tau; ties at tau filled ascending-j
//         (matches lax.top_k lower-index-first tie rule).
// ---------------------------------------------------------------------------
__global__ __launch_bounds__(256) void knn_kernel(const float* __restrict__ pos,
                                                  int* __restrict__ srcidx) {
    __shared__ float4 sp[NPG];   // x, y, z, |p|^2

    const int g    = blockIdx.x >> 2;
    const int base = g * NPG;

    for (int t = threadIdx.x; t < NPG; t += 256) {
        float x = pos[(size_t)(base + t) * 3 + 0];
        float y = pos[(size_t)(base + t) * 3 + 1];
        float z = pos[(size_t)(base + t) * 3 + 2];
        float sq = __fadd_rn(__fadd_rn(__fmul_rn(x, x), __fmul_rn(y, y)),
                             __fmul_rn(z, z));
        sp[t] = make_float4(x, y, z, sq);
    }
    __syncthreads();

    const int li = ((blockIdx.x & 3) << 8) + threadIdx.x;   // local node 0..1023
    const float4 qi = sp[li];

    float s[KNN];
#pragma unroll
    for (int p = 0; p < KNN; ++p) s[p] = INFINITY;

    // pass 1: values only
    for (int j = 0; j < NPG; ++j) {
        if (j == li) continue;
        float4 qj = sp[j];
        float d2 = d2_exact(qi.x, qi.y, qi.z, qi.w, qj.x, qj.y, qj.z, qj.w);
        if (d2 < s[KNN - 1]) {
#pragma unroll
            for (int p = KNN - 1; p >= 1; --p)
                s[p] = __builtin_amdgcn_fmed3f(s[p - 1], d2, s[p]);
            s[0] = fminf(s[0], d2);
        }
    }

    const float tau = s[KNN - 1];
    const int outbase = (base + li) * KNN;

    // pass 2: emit
    int cnt = 0;
    int tcnt = 0;
    int tie0 = 0, tie1 = 0, tie2 = 0, tie3 = 0;
    for (int j = 0; j < NPG; ++j) {
        if (j == li) continue;
        float4 qj = sp[j];
        float d2 = d2_exact(qi.x, qi.y, qi.z, qi.w, qj.x, qj.y, qj.z, qj.w);
        if (d2 < tau) {
            srcidx[outbase + cnt] = base + j;
            ++cnt;
        } else if (d2 == tau) {
            if (tcnt == 0) tie0 = j;
            else if (tcnt == 1) tie1 = j;
            else if (tcnt == 2) tie2 = j;
            else if (tcnt == 3) tie3 = j;
            ++tcnt;
        }
    }
    const int need = KNN - cnt;
    if (need > 0) srcidx[outbase + cnt + 0] = base + tie0;
    if (need > 1) srcidx[outbase + cnt + 1] = base + tie1;
    if (need > 2) srcidx[outbase + cnt + 2] = base + tie2;
    if (need > 3) srcidx[outbase + cnt + 3] = base + tie3;
}

// ---------------------------------------------------------------------------
// node embedding: h = silu(pos @ pe_w1 + pe_b1) @ pe_w2 + pe_b2
// ---------------------------------------------------------------------------
__global__ __launch_bounds__(256) void embed_kernel(
    const float* __restrict__ pos,
    const float* __restrict__ w1, const float* __restrict__ b1,
    const float* __restrict__ w2, const float* __restrict__ b2,
    float* __restrict__ h) {
    const int i = blockIdx.x * 256 + threadIdx.x;
    if (i >= NTOT) return;
    const float x = pos[3 * (size_t)i + 0];
    const float y = pos[3 * (size_t)i + 1];
    const float z = pos[3 * (size_t)i + 2];

    float t[HD];
#pragma unroll
    for (int o = 0; o < HD; ++o)
        t[o] = silu_f(b1[o] + x * w1[0 * HD + o] + y * w1[1 * HD + o] + z * w1[2 * HD + o]);

    float r[HD];
#pragma unroll
    for (int o = 0; o < HD; ++o) r[o] = b2[o];
#pragma unroll
    for (int c = 0; c < HD; ++c) {
        const float a = t[c];
#pragma unroll
        for (int o = 0; o < HD; ++o) r[o] += a * w2[c * HD + o];
    }
    float4* hp = (float4*)(h + (size_t)i * HD);
    hp[0] = make_float4(r[0], r[1], r[2], r[3]);
    hp[1] = make_float4(r[4], r[5], r[6], r[7]);
    hp[2] = make_float4(r[8], r[9], r[10], r[11]);
    hp[3] = make_float4(r[12], r[13], r[14], r[15]);
}

// ---------------------------------------------------------------------------
// one message-passing layer, fully fused, one thread per node.
// ---------------------------------------------------------------------------
__global__ __launch_bounds__(256, 1) void layer_kernel(
    const float* __restrict__ pos, const int* __restrict__ srcidx,
    const float* __restrict__ h_in, float* __restrict__ h_out,
    const float* __restrict__ ew1, const float* __restrict__ eb1,
    const float* __restrict__ ew2, const float* __restrict__ eb2,
    const float* __restrict__ ew3, const float* __restrict__ eb3,
    const float* __restrict__ nw1, const float* __restrict__ nb1,
    const float* __restrict__ nw2, const float* __restrict__ nb2) {
    const int i = blockIdx.x * 256 + threadIdx.x;
    if (i >= NTOT) return;

    float hi[HD];
    {
        const float4* p = (const float4*)(h_in + (size_t)i * HD);
        float4 a = p[0], b = p[1], c = p[2], d = p[3];
        hi[0] = a.x; hi[1] = a.y; hi[2] = a.z; hi[3] = a.w;
        hi[4] = b.x; hi[5] = b.y; hi[6] = b.z; hi[7] = b.w;
        hi[8] = c.x; hi[9] = c.y; hi[10] = c.z; hi[11] = c.w;
        hi[12] = d.x; hi[13] = d.y; hi[14] = d.z; hi[15] = d.w;
    }
    const float pix = pos[3 * (size_t)i + 0];
    const float piy = pos[3 * (size_t)i + 1];
    const float piz = pos[3 * (size_t)i + 2];
    const float ni  = sqrtf(pix * pix + piy * piy + piz * piz);
    const float rni = 1.0f / (ni + 1e-8f);
    const float oix = pix * rni, oiy = piy * rni, oiz = piz * rni;

    float sacc[HD], macc[HD];
#pragma unroll
    for (int o = 0; o < HD; ++o) { sacc[o] = 0.0f; macc[o] = -INFINITY; }

#pragma unroll 1
    for (int k = 0; k < KNN; ++k) {
        const int j = srcidx[(size_t)i * KNN + k];

        const float pjx = pos[3 * (size_t)j + 0];
        const float pjy = pos[3 * (size_t)j + 1];
        const float pjz = pos[3 * (size_t)j + 2];
        const float rx = pjx - pix, ry = pjy - piy, rz = pjz - piz;
        const float dist = sqrtf(rx * rx + ry * ry + rz * rz);
        const float rid  = 1.0f / (dist + 1e-8f);
        const float dirx = rx * rid, diry = ry * rid, dirz = rz * rid;
        const float nj  = sqrtf(pjx * pjx + pjy * pjy + pjz * pjz);
        const float rnj = 1.0f / (nj + 1e-8f);
        const float dotf = oix * (pjx * rnj) + oiy * (pjy * rnj) + oiz * (pjz * rnj);

        float hj[HD];
        {
            const float4* p = (const float4*)(h_in + (size_t)j * HD);
            float4 a = p[0], b = p[1], c = p[2], d = p[3];
            hj[0] = a.x; hj[1] = a.y; hj[2] = a.z; hj[3] = a.w;
            hj[4] = b.x; hj[5] = b.y; hj[6] = b.z; hj[7] = b.w;
            hj[8] = c.x; hj[9] = c.y; hj[10] = c.z; hj[11] = c.w;
            hj[12] = d.x; hj[13] = d.y; hj[14] = d.z; hj[15] = d.w;
        }

        // t1 = silu(ef @ ew1 + eb1), ef = [hi(16), hj(16), dist, dir(3), dot]
        float t1[32];
#pragma unroll
        for (int o = 0; o < 32; ++o) t1[o] = eb1[o];
#pragma unroll
        for (int c = 0; c < HD; ++c) {
            const float a = hi[c], b = hj[c];
#pragma unroll
            for (int o = 0; o < 32; ++o)
                t1[o] += a * ew1[c * 32 + o] + b * ew1[(HD + c) * 32 + o];
        }
#pragma unroll
        for (int o = 0; o < 32; ++o)
            t1[o] += dist * ew1[32 * 32 + o] + dirx * ew1[33 * 32 + o]
                   + diry * ew1[34 * 32 + o] + dirz * ew1[35 * 32 + o]
                   + dotf * ew1[36 * 32 + o];
#pragma unroll
        for (int o = 0; o < 32; ++o) t1[o] = silu_f(t1[o]);

        // t2 = silu(t1 @ ew2 + eb2)
        float t2[HD];
#pragma unroll
        for (int o = 0; o < HD; ++o) t2[o] = eb2[o];
#pragma unroll
        for (int c = 0; c < 32; ++c) {
            const float a = t1[c];
#pragma unroll
            for (int o = 0; o < HD; ++o) t2[o] += a * ew2[c * HD + o];
        }
#pragma unroll
        for (int o = 0; o < HD; ++o) t2[o] = silu_f(t2[o]);

        // m = t2 @ ew3 + eb3 ; fold into sum/max accumulators
#pragma unroll
        for (int o = 0; o < HD; ++o) {
            float mm = eb3[o];
#pragma unroll
            for (int c = 0; c < HD; ++c) mm += t2[c] * ew3[c * HD + o];
            sacc[o] += mm;
            macc[o] = fmaxf(macc[o], mm);
        }
    }

    // node update: upd = silu([hi, mean, max] @ nw1 + nb1) @ nw2 + nb2
    float u1[32];
#pragma unroll
    for (int o = 0; o < 32; ++o) u1[o] = nb1[o];
#pragma unroll
    for (int c = 0; c < HD; ++c) {
        const float a = hi[c];
        const float b = sacc[c] / 20.0f;
        const float d = macc[c];
#pragma unroll
        for (int o = 0; o < 32; ++o)
            u1[o] += a * nw1[c * 32 + o] + b * nw1[(HD + c) * 32 + o]
                   + d * nw1[(2 * HD + c) * 32 + o];
    }
#pragma unroll
    for (int o = 0; o < 32; ++o) u1[o] = silu_f(u1[o]);

    float u2[HD];
#pragma unroll
    for (int o = 0; o < HD; ++o) u2[o] = nb2[o];
#pragma unroll
    for (int c = 0; c < 32; ++c) {
        const float a = u1[c];
#pragma unroll
        for (int o = 0; o < HD; ++o) u2[o] += a * nw2[c * HD + o];
    }

    float4* outp = (float4*)(h_out + (size_t)i * HD);
    outp[0] = make_float4(hi[0] + u2[0], hi[1] + u2[1], hi[2] + u2[2], hi[3] + u2[3]);
    outp[1] = make_float4(hi[4] + u2[4], hi[5] + u2[5], hi[6] + u2[6], hi[7] + u2[7]);
    outp[2] = make_float4(hi[8] + u2[8], hi[9] + u2[9], hi[10] + u2[10], hi[11] + u2[11]);
    outp[3] = make_float4(hi[12] + u2[12], hi[13] + u2[13], hi[14] + u2[14], hi[15] + u2[15]);
}

// ---------------------------------------------------------------------------
// output head: out = silu(silu(h@ow1+ob1)@ow2+ob2)@ow3+ob3
// ---------------------------------------------------------------------------
__global__ __launch_bounds__(256) void out_kernel(
    const float* __restrict__ h,
    const float* __restrict__ ow1, const float* __restrict__ ob1,
    const float* __restrict__ ow2, const float* __restrict__ ob2,
    const float* __restrict__ ow3, const float* __restrict__ ob3,
    float* __restrict__ out) {
    const int i = blockIdx.x * 256 + threadIdx.x;
    if (i >= NTOT) return;

    float hv[HD];
    {
        const float4* p = (const float4*)(h + (size_t)i * HD);
        float4 a = p[0], b = p[1], c = p[2], d = p[3];
        hv[0] = a.x; hv[1] = a.y; hv[2] = a.z; hv[3] = a.w;
        hv[4] = b.x; hv[5] = b.y; hv[6] = b.z; hv[7] = b.w;
        hv[8] = c.x; hv[9] = c.y; hv[10] = c.z; hv[11] = c.w;
        hv[12] = d.x; hv[13] = d.y; hv[14] = d.z; hv[15] = d.w;
    }

    float t1[HD];
#pragma unroll
    for (int o = 0; o < HD; ++o) t1[o] = ob1[o];
#pragma unroll
    for (int c = 0; c < HD; ++c) {
        const float a = hv[c];
#pragma unroll
        for (int o = 0; o < HD; ++o) t1[o] += a * ow1[c * HD + o];
    }
#pragma unroll
    for (int o = 0; o < HD; ++o) t1[o] = silu_f(t1[o]);

    float t2[8];
#pragma unroll
    for (int o = 0; o < 8; ++o) t2[o] = ob2[o];
#pragma unroll
    for (int c = 0; c < HD; ++c) {
        const float a = t1[c];
#pragma unroll
        for (int o = 0; o < 8; ++o) t2[o] += a * ow2[c * 8 + o];
    }
#pragma unroll
    for (int o = 0; o < 8; ++o) t2[o] = silu_f(t2[o]);

    float r0 = ob3[0], r1 = ob3[1], r2 = ob3[2];
#pragma unroll
    for (int c = 0; c < 8; ++c) {
        r0 += t2[c] * ow3[c * 3 + 0];
        r1 += t2[c] * ow3[c * 3 + 1];
        r2 += t2[c] * ow3[c * 3 + 2];
    }
    out[3 * (size_t)i + 0] = r0;
    out[3 * (size_t)i + 1] = r1;
    out[3 * (size_t)i + 2] = r2;
}

// ---------------------------------------------------------------------------
extern "C" void kernel_launch(void* const* d_in, const int* in_sizes, int n_in,
                              void* d_out, int out_size, void* d_ws, size_t ws_size,
                              hipStream_t stream) {
    const float* pos   = (const float*)d_in[0];
    const float* pe_w1 = (const float*)d_in[1];
    const float* pe_b1 = (const float*)d_in[2];
    const float* pe_w2 = (const float*)d_in[3];
    const float* pe_b2 = (const float*)d_in[4];
    const float* ew1   = (const float*)d_in[5];
    const float* eb1   = (const float*)d_in[6];
    const float* ew2   = (const float*)d_in[7];
    const float* eb2   = (const float*)d_in[8];
    const float* ew3   = (const float*)d_in[9];
    const float* eb3   = (const float*)d_in[10];
    const float* nw1   = (const float*)d_in[11];
    const float* nb1   = (const float*)d_in[12];
    const float* nw2   = (const float*)d_in[13];
    const float* nb2   = (const float*)d_in[14];
    const float* ow1   = (const float*)d_in[15];
    const float* ob1   = (const float*)d_in[16];
    const float* ow2   = (const float*)d_in[17];
    const float* ob2   = (const float*)d_in[18];
    const float* ow3   = (const float*)d_in[19];
    const float* ob3   = (const float*)d_in[20];

    char* ws = (char*)d_ws;
    int*   srcidx = (int*)ws;                                    // NTOT*KNN ints
    float* h0 = (float*)(ws + (size_t)NTOT * KNN * sizeof(int)); // NTOT*HD
    float* h1 = h0 + (size_t)NTOT * HD;                          // NTOT*HD

    knn_kernel<<<NGRAPH * 4, 256, 0, stream>>>(pos, srcidx);
    embed_kernel<<<NTOT / 256, 256, 0, stream>>>(pos, pe_w1, pe_b1, pe_w2, pe_b2, h0);

    for (int l = 0; l < 4; ++l) {
        const float* hin  = (l & 1) ? h1 : h0;
        float*       hout = (l & 1) ? h0 : h1;
        layer_kernel<<<NTOT / 256, 256, 0, stream>>>(
            pos, srcidx, hin, hout,
            ew1 + (size_t)l * 37 * 32, eb1 + (size_t)l * 32,
            ew2 + (size_t)l * 32 * 16, eb2 + (size_t)l * 16,
            ew3 + (size_t)l * 16 * 16, eb3 + (size_t)l * 16,
            nw1 + (size_t)l * 48 * 32, nb1 + (size_t)l * 32,
            nw2 + (size_t)l * 32 * 16, nb2 + (size_t)l * 16);
    }

    out_kernel<<<NTOT / 256, 256, 0, stream>>>(h0, ow1, ob1, ow2, ob2, ow3, ob3,
                                               (float*)d_out);
}

// Round 2
// 1339.831 us; speedup vs baseline: 3.0818x; 3.0818x over previous
//
#include <hip/hip_runtime.h>
#include <math.h>

#define NPG    1024
#define KNN    20
#define NGRAPH 64
#define NTOT   (NGRAPH * NPG)   // 65536
#define HD     16
#define EPB    16               // nodes per edge-block
#define TPB    (EPB * KNN)      // 320 threads per edge-block
#define SMSTR  17               // padded LDS row stride for m staging

// ---------------------------------------------------------------------------
__device__ __forceinline__ float silu_f(float x) {
    float s = 1.0f / (1.0f + __expf(-x));
    return x * s;
}

__device__ __forceinline__ float d2_exact(float xi, float yi, float zi, float sqi,
                                          float xj, float yj, float zj, float sqj) {
    float dot = __fadd_rn(__fadd_rn(__fmul_rn(xi, xj), __fmul_rn(yi, yj)),
                          __fmul_rn(zi, zj));
    return __fsub_rn(__fadd_rn(sqi, sqj), __fmul_rn(2.0f, dot));
}

// ---------------------------------------------------------------------------
// KNN (unchanged from R0 — correct, not yet the bottleneck)
// ---------------------------------------------------------------------------
__global__ __launch_bounds__(256) void knn_kernel(const float* __restrict__ pos,
                                                  int* __restrict__ srcidx) {
    __shared__ float4 sp[NPG];

    const int g    = blockIdx.x >> 2;
    const int base = g * NPG;

    for (int t = threadIdx.x; t < NPG; t += 256) {
        float x = pos[(size_t)(base + t) * 3 + 0];
        float y = pos[(size_t)(base + t) * 3 + 1];
        float z = pos[(size_t)(base + t) * 3 + 2];
        float sq = __fadd_rn(__fadd_rn(__fmul_rn(x, x), __fmul_rn(y, y)),
                             __fmul_rn(z, z));
        sp[t] = make_float4(x, y, z, sq);
    }
    __syncthreads();

    const int li = ((blockIdx.x & 3) << 8) + threadIdx.x;
    const float4 qi = sp[li];

    float s[KNN];
#pragma unroll
    for (int p = 0; p < KNN; ++p) s[p] = INFINITY;

    for (int j = 0; j < NPG; ++j) {
        if (j == li) continue;
        float4 qj = sp[j];
        float d2 = d2_exact(qi.x, qi.y, qi.z, qi.w, qj.x, qj.y, qj.z, qj.w);
        if (d2 < s[KNN - 1]) {
#pragma unroll
            for (int p = KNN - 1; p >= 1; --p)
                s[p] = __builtin_amdgcn_fmed3f(s[p - 1], d2, s[p]);
            s[0] = fminf(s[0], d2);
        }
    }

    const float tau = s[KNN - 1];
    const int outbase = (base + li) * KNN;

    int cnt = 0;
    int tcnt = 0;
    int tie0 = 0, tie1 = 0, tie2 = 0, tie3 = 0;
    for (int j = 0; j < NPG; ++j) {
        if (j == li) continue;
        float4 qj = sp[j];
        float d2 = d2_exact(qi.x, qi.y, qi.z, qi.w, qj.x, qj.y, qj.z, qj.w);
        if (d2 < tau) {
            srcidx[outbase + cnt] = base + j;
            ++cnt;
        } else if (d2 == tau) {
            if (tcnt == 0) tie0 = j;
            else if (tcnt == 1) tie1 = j;
            else if (tcnt == 2) tie2 = j;
            else if (tcnt == 3) tie3 = j;
            ++tcnt;
        }
    }
    const int need = KNN - cnt;
    if (need > 0) srcidx[outbase + cnt + 0] = base + tie0;
    if (need > 1) srcidx[outbase + cnt + 1] = base + tie1;
    if (need > 2) srcidx[outbase + cnt + 2] = base + tie2;
    if (need > 3) srcidx[outbase + cnt + 3] = base + tie3;
}

// ---------------------------------------------------------------------------
// embedding
// ---------------------------------------------------------------------------
__global__ __launch_bounds__(256) void embed_kernel(
    const float* __restrict__ pos,
    const float* __restrict__ w1, const float* __restrict__ b1,
    const float* __restrict__ w2, const float* __restrict__ b2,
    float* __restrict__ h) {
    const int i = blockIdx.x * 256 + threadIdx.x;
    if (i >= NTOT) return;
    const float x = pos[3 * (size_t)i + 0];
    const float y = pos[3 * (size_t)i + 1];
    const float z = pos[3 * (size_t)i + 2];

    float t[HD];
#pragma unroll
    for (int o = 0; o < HD; ++o)
        t[o] = silu_f(b1[o] + x * w1[0 * HD + o] + y * w1[1 * HD + o] + z * w1[2 * HD + o]);

    float r[HD];
#pragma unroll
    for (int o = 0; o < HD; ++o) r[o] = b2[o];
#pragma unroll
    for (int c = 0; c < HD; ++c) {
        const float a = t[c];
#pragma unroll
        for (int o = 0; o < HD; ++o) r[o] += a * w2[c * HD + o];
    }
    float4* hp = (float4*)(h + (size_t)i * HD);
    hp[0] = make_float4(r[0], r[1], r[2], r[3]);
    hp[1] = make_float4(r[4], r[5], r[6], r[7]);
    hp[2] = make_float4(r[8], r[9], r[10], r[11]);
    hp[3] = make_float4(r[12], r[13], r[14], r[15]);
}

// ---------------------------------------------------------------------------
// edge kernel: one thread per edge. Weights in LDS (wave-uniform broadcast
// reads). Per-block reduction (16 nodes x 20 edges) -> mean/max to global.
// ---------------------------------------------------------------------------
__global__ __launch_bounds__(TPB) void edge_kernel(
    const float* __restrict__ pos, const int* __restrict__ srcidx,
    const float* __restrict__ h_in,
    const float* __restrict__ ew1, const float* __restrict__ eb1,
    const float* __restrict__ ew2, const float* __restrict__ eb2,
    const float* __restrict__ ew3, const float* __restrict__ eb3,
    float* __restrict__ msum, float* __restrict__ mmax) {
    __shared__ float w1s[37 * 32];
    __shared__ float b1s[32];
    __shared__ float w2s[32 * HD];
    __shared__ float b2s[HD];
    __shared__ float w3s[HD * HD];
    __shared__ float b3s[HD];
    __shared__ float sm[TPB * SMSTR];

    const int t = threadIdx.x;
    for (int u = t; u < 37 * 32; u += TPB) w1s[u] = ew1[u];
    for (int u = t; u < 32; u += TPB)      b1s[u] = eb1[u];
    for (int u = t; u < 32 * HD; u += TPB) w2s[u] = ew2[u];
    for (int u = t; u < HD; u += TPB)      b2s[u] = eb2[u];
    for (int u = t; u < HD * HD; u += TPB) w3s[u] = ew3[u];
    for (int u = t; u < HD; u += TPB)      b3s[u] = eb3[u];

    const int e = blockIdx.x * TPB + t;     // global edge id
    const int i = e / KNN;                  // dst node
    const int j = srcidx[e];                // src node

    const float pix = pos[3 * (size_t)i + 0];
    const float piy = pos[3 * (size_t)i + 1];
    const float piz = pos[3 * (size_t)i + 2];
    const float pjx = pos[3 * (size_t)j + 0];
    const float pjy = pos[3 * (size_t)j + 1];
    const float pjz = pos[3 * (size_t)j + 2];

    const float rx = pjx - pix, ry = pjy - piy, rz = pjz - piz;
    const float dist = sqrtf(rx * rx + ry * ry + rz * rz);
    const float rid  = 1.0f / (dist + 1e-8f);
    const float dirx = rx * rid, diry = ry * rid, dirz = rz * rid;
    const float ni  = sqrtf(pix * pix + piy * piy + piz * piz);
    const float rni = 1.0f / (ni + 1e-8f);
    const float nj  = sqrtf(pjx * pjx + pjy * pjy + pjz * pjz);
    const float rnj = 1.0f / (nj + 1e-8f);
    const float dotf = (pix * rni) * (pjx * rnj) + (piy * rni) * (pjy * rnj)
                     + (piz * rni) * (pjz * rnj);

    float hi[HD], hj[HD];
    {
        const float4* p = (const float4*)(h_in + (size_t)i * HD);
        float4 a = p[0], b = p[1], c = p[2], d = p[3];
        hi[0] = a.x; hi[1] = a.y; hi[2] = a.z; hi[3] = a.w;
        hi[4] = b.x; hi[5] = b.y; hi[6] = b.z; hi[7] = b.w;
        hi[8] = c.x; hi[9] = c.y; hi[10] = c.z; hi[11] = c.w;
        hi[12] = d.x; hi[13] = d.y; hi[14] = d.z; hi[15] = d.w;
    }
    {
        const float4* p = (const float4*)(h_in + (size_t)j * HD);
        float4 a = p[0], b = p[1], c = p[2], d = p[3];
        hj[0] = a.x; hj[1] = a.y; hj[2] = a.z; hj[3] = a.w;
        hj[4] = b.x; hj[5] = b.y; hj[6] = b.z; hj[7] = b.w;
        hj[8] = c.x; hj[9] = c.y; hj[10] = c.z; hj[11] = c.w;
        hj[12] = d.x; hj[13] = d.y; hj[14] = d.z; hj[15] = d.w;
    }

    __syncthreads();   // weights staged

    // t1 = silu(ef @ ew1 + eb1)
    float t1[32];
#pragma unroll
    for (int o = 0; o < 32; ++o) t1[o] = b1s[o];
#pragma unroll
    for (int c = 0; c < HD; ++c) {
        const float a = hi[c], b = hj[c];
#pragma unroll
        for (int o = 0; o < 32; ++o)
            t1[o] += a * w1s[c * 32 + o] + b * w1s[(HD + c) * 32 + o];
    }
#pragma unroll
    for (int o = 0; o < 32; ++o)
        t1[o] += dist * w1s[32 * 32 + o] + dirx * w1s[33 * 32 + o]
               + diry * w1s[34 * 32 + o] + dirz * w1s[35 * 32 + o]
               + dotf * w1s[36 * 32 + o];
#pragma unroll
    for (int o = 0; o < 32; ++o) t1[o] = silu_f(t1[o]);

    // t2 = silu(t1 @ ew2 + eb2)
    float t2[HD];
#pragma unroll
    for (int o = 0; o < HD; ++o) t2[o] = b2s[o];
#pragma unroll
    for (int c = 0; c < 32; ++c) {
        const float a = t1[c];
#pragma unroll
        for (int o = 0; o < HD; ++o) t2[o] += a * w2s[c * HD + o];
    }
#pragma unroll
    for (int o = 0; o < HD; ++o) t2[o] = silu_f(t2[o]);

    // m = t2 @ ew3 + eb3  -> staged in LDS
#pragma unroll
    for (int o = 0; o < HD; ++o) {
        float mm = b3s[o];
#pragma unroll
        for (int c = 0; c < HD; ++c) mm += t2[c] * w3s[c * HD + o];
        sm[t * SMSTR + o] = mm;
    }

    __syncthreads();

    // reduce over k for the block's 16 nodes: thread (n, o)
    if (t < EPB * HD) {
        const int n = t >> 4;
        const int o = t & 15;
        float sum = 0.0f;
        float mx  = -INFINITY;
#pragma unroll
        for (int k = 0; k < KNN; ++k) {
            float v = sm[(n * KNN + k) * SMSTR + o];
            sum += v;
            mx = fmaxf(mx, v);
        }
        const int node = blockIdx.x * EPB + n;
        msum[(size_t)node * HD + o] = sum / 20.0f;
        mmax[(size_t)node * HD + o] = mx;
    }
}

// ---------------------------------------------------------------------------
// node kernel: upd = silu([h, mean, max] @ nw1 + nb1) @ nw2 + nb2 ; h += upd
// ---------------------------------------------------------------------------
__global__ __launch_bounds__(256) void node_kernel(
    const float* __restrict__ h_in,
    const float* __restrict__ msum, const float* __restrict__ mmax,
    const float* __restrict__ nw1, const float* __restrict__ nb1,
    const float* __restrict__ nw2, const float* __restrict__ nb2,
    float* __restrict__ h_out) {
    __shared__ float w1s[48 * 32];
    __shared__ float b1s[32];
    __shared__ float w2s[32 * HD];
    __shared__ float b2s[HD];

    const int t = threadIdx.x;
    for (int u = t; u < 48 * 32; u += 256) w1s[u] = nw1[u];
    for (int u = t; u < 32; u += 256)      b1s[u] = nb1[u];
    for (int u = t; u < 32 * HD; u += 256) w2s[u] = nw2[u];
    for (int u = t; u < HD; u += 256)      b2s[u] = nb2[u];

    const int i = blockIdx.x * 256 + t;

    float hi[HD], me[HD], mx[HD];
    {
        const float4* p = (const float4*)(h_in + (size_t)i * HD);
        float4 a = p[0], b = p[1], c = p[2], d = p[3];
        hi[0] = a.x; hi[1] = a.y; hi[2] = a.z; hi[3] = a.w;
        hi[4] = b.x; hi[5] = b.y; hi[6] = b.z; hi[7] = b.w;
        hi[8] = c.x; hi[9] = c.y; hi[10] = c.z; hi[11] = c.w;
        hi[12] = d.x; hi[13] = d.y; hi[14] = d.z; hi[15] = d.w;
    }
    {
        const float4* p = (const float4*)(msum + (size_t)i * HD);
        float4 a = p[0], b = p[1], c = p[2], d = p[3];
        me[0] = a.x; me[1] = a.y; me[2] = a.z; me[3] = a.w;
        me[4] = b.x; me[5] = b.y; me[6] = b.z; me[7] = b.w;
        me[8] = c.x; me[9] = c.y; me[10] = c.z; me[11] = c.w;
        me[12] = d.x; me[13] = d.y; me[14] = d.z; me[15] = d.w;
    }
    {
        const float4* p = (const float4*)(mmax + (size_t)i * HD);
        float4 a = p[0], b = p[1], c = p[2], d = p[3];
        mx[0] = a.x; mx[1] = a.y; mx[2] = a.z; mx[3] = a.w;
        mx[4] = b.x; mx[5] = b.y; mx[6] = b.z; mx[7] = b.w;
        mx[8] = c.x; mx[9] = c.y; mx[10] = c.z; mx[11] = c.w;
        mx[12] = d.x; mx[13] = d.y; mx[14] = d.z; mx[15] = d.w;
    }

    __syncthreads();

    float u1[32];
#pragma unroll
    for (int o = 0; o < 32; ++o) u1[o] = b1s[o];
#pragma unroll
    for (int c = 0; c < HD; ++c) {
        const float a = hi[c], b = me[c], d = mx[c];
#pragma unroll
        for (int o = 0; o < 32; ++o)
            u1[o] += a * w1s[c * 32 + o] + b * w1s[(HD + c) * 32 + o]
                   + d * w1s[(2 * HD + c) * 32 + o];
    }
#pragma unroll
    for (int o = 0; o < 32; ++o) u1[o] = silu_f(u1[o]);

    float u2[HD];
#pragma unroll
    for (int o = 0; o < HD; ++o) u2[o] = b2s[o];
#pragma unroll
    for (int c = 0; c < 32; ++c) {
        const float a = u1[c];
#pragma unroll
        for (int o = 0; o < HD; ++o) u2[o] += a * w2s[c * HD + o];
    }

    float4* outp = (float4*)(h_out + (size_t)i * HD);
    outp[0] = make_float4(hi[0] + u2[0], hi[1] + u2[1], hi[2] + u2[2], hi[3] + u2[3]);
    outp[1] = make_float4(hi[4] + u2[4], hi[5] + u2[5], hi[6] + u2[6], hi[7] + u2[7]);
    outp[2] = make_float4(hi[8] + u2[8], hi[9] + u2[9], hi[10] + u2[10], hi[11] + u2[11]);
    outp[3] = make_float4(hi[12] + u2[12], hi[13] + u2[13], hi[14] + u2[14], hi[15] + u2[15]);
}

// ---------------------------------------------------------------------------
// output head
// ---------------------------------------------------------------------------
__global__ __launch_bounds__(256) void out_kernel(
    const float* __restrict__ h,
    const float* __restrict__ ow1, const float* __restrict__ ob1,
    const float* __restrict__ ow2, const float* __restrict__ ob2,
    const float* __restrict__ ow3, const float* __restrict__ ob3,
    float* __restrict__ out) {
    const int i = blockIdx.x * 256 + threadIdx.x;
    if (i >= NTOT) return;

    float hv[HD];
    {
        const float4* p = (const float4*)(h + (size_t)i * HD);
        float4 a = p[0], b = p[1], c = p[2], d = p[3];
        hv[0] = a.x; hv[1] = a.y; hv[2] = a.z; hv[3] = a.w;
        hv[4] = b.x; hv[5] = b.y; hv[6] = b.z; hv[7] = b.w;
        hv[8] = c.x; hv[9] = c.y; hv[10] = c.z; hv[11] = c.w;
        hv[12] = d.x; hv[13] = d.y; hv[14] = d.z; hv[15] = d.w;
    }

    float t1[HD];
#pragma unroll
    for (int o = 0; o < HD; ++o) t1[o] = ob1[o];
#pragma unroll
    for (int c = 0; c < HD; ++c) {
        const float a = hv[c];
#pragma unroll
        for (int o = 0; o < HD; ++o) t1[o] += a * ow1[c * HD + o];
    }
#pragma unroll
    for (int o = 0; o < HD; ++o) t1[o] = silu_f(t1[o]);

    float t2[8];
#pragma unroll
    for (int o = 0; o < 8; ++o) t2[o] = ob2[o];
#pragma unroll
    for (int c = 0; c < HD; ++c) {
        const float a = t1[c];
#pragma unroll
        for (int o = 0; o < 8; ++o) t2[o] += a * ow2[c * 8 + o];
    }
#pragma unroll
    for (int o = 0; o < 8; ++o) t2[o] = silu_f(t2[o]);

    float r0 = ob3[0], r1 = ob3[1], r2 = ob3[2];
#pragma unroll
    for (int c = 0; c < 8; ++c) {
        r0 += t2[c] * ow3[c * 3 + 0];
        r1 += t2[c] * ow3[c * 3 + 1];
        r2 += t2[c] * ow3[c * 3 + 2];
    }
    out[3 * (size_t)i + 0] = r0;
    out[3 * (size_t)i + 1] = r1;
    out[3 * (size_t)i + 2] = r2;
}

// ---------------------------------------------------------------------------
extern "C" void kernel_launch(void* const* d_in, const int* in_sizes, int n_in,
                              void* d_out, int out_size, void* d_ws, size_t ws_size,
                              hipStream_t stream) {
    const float* pos   = (const float*)d_in[0];
    const float* pe_w1 = (const float*)d_in[1];
    const float* pe_b1 = (const float*)d_in[2];
    const float* pe_w2 = (const float*)d_in[3];
    const float* pe_b2 = (const float*)d_in[4];
    const float* ew1   = (const float*)d_in[5];
    const float* eb1   = (const float*)d_in[6];
    const float* ew2   = (const float*)d_in[7];
    const float* eb2   = (const float*)d_in[8];
    const float* ew3   = (const float*)d_in[9];
    const float* eb3   = (const float*)d_in[10];
    const float* nw1   = (const float*)d_in[11];
    const float* nb1   = (const float*)d_in[12];
    const float* nw2   = (const float*)d_in[13];
    const float* nb2   = (const float*)d_in[14];
    const float* ow1   = (const float*)d_in[15];
    const float* ob1   = (const float*)d_in[16];
    const float* ow2   = (const float*)d_in[17];
    const float* ob2   = (const float*)d_in[18];
    const float* ow3   = (const float*)d_in[19];
    const float* ob3   = (const float*)d_in[20];

    char* ws = (char*)d_ws;
    int*   srcidx = (int*)ws;                                     // NTOT*KNN ints
    float* h0   = (float*)(ws + (size_t)NTOT * KNN * sizeof(int));
    float* h1   = h0 + (size_t)NTOT * HD;
    float* msum = h1 + (size_t)NTOT * HD;
    float* mmax = msum + (size_t)NTOT * HD;

    knn_kernel<<<NGRAPH * 4, 256, 0, stream>>>(pos, srcidx);
    embed_kernel<<<NTOT / 256, 256, 0, stream>>>(pos, pe_w1, pe_b1, pe_w2, pe_b2, h0);

    const int eblocks = (NTOT * KNN) / TPB;   // 4096
    for (int l = 0; l < 4; ++l) {
        const float* hin  = (l & 1) ? h1 : h0;
        float*       hout = (l & 1) ? h0 : h1;
        edge_kernel<<<eblocks, TPB, 0, stream>>>(
            pos, srcidx, hin,
            ew1 + (size_t)l * 37 * 32, eb1 + (size_t)l * 32,
            ew2 + (size_t)l * 32 * 16, eb2 + (size_t)l * 16,
            ew3 + (size_t)l * 16 * 16, eb3 + (size_t)l * 16,
            msum, mmax);
        node_kernel<<<NTOT / 256, 256, 0, stream>>>(
            hin, msum, mmax,
            nw1 + (size_t)l * 48 * 32, nb1 + (size_t)l * 32,
            nw2 + (size_t)l * 32 * 16, nb2 + (size_t)l * 16,
            hout);
    }

    out_kernel<<<NTOT / 256, 256, 0, stream>>>(h0, ow1, ob1, ow2, ob2, ow3, ob3,
                                               (float*)d_out);
}

// Round 3
// 1262.381 us; speedup vs baseline: 3.2709x; 1.0614x over previous
//
#include <hip/hip_runtime.h>
#include <math.h>

#define NPG    1024
#define KNN    20
#define NGRAPH 64
#define NTOT   (NGRAPH * NPG)   // 65536
#define HD     16
#define EPB    16               // nodes per layer-block
#define TPB    (EPB * KNN)      // 320 threads per layer-block

// ---------------------------------------------------------------------------
__device__ __forceinline__ float silu_f(float x) {
    float s = 1.0f / (1.0f + __expf(-x));
    return x * s;
}

__device__ __forceinline__ float d2_exact(float xi, float yi, float zi, float sqi,
                                          float xj, float yj, float zj, float sqj) {
    float dot = __fadd_rn(__fadd_rn(__fmul_rn(xi, xj), __fmul_rn(yi, yj)),
                          __fmul_rn(zi, zj));
    return __fsub_rn(__fadd_rn(sqi, sqj), __fmul_rn(2.0f, dot));
}

// ---------------------------------------------------------------------------
// KNN: branch-free med3 insertion (chain is a provable no-op when d2>=s[19]),
// self-loop removed via cndmask, unrolled x4 so ds_reads pipeline ahead.
// ---------------------------------------------------------------------------
__global__ __launch_bounds__(256) void knn_kernel(const float* __restrict__ pos,
                                                  int* __restrict__ srcidx) {
    __shared__ float4 sp[NPG];

    const int g    = blockIdx.x >> 2;
    const int base = g * NPG;

    for (int t = threadIdx.x; t < NPG; t += 256) {
        float x = pos[(size_t)(base + t) * 3 + 0];
        float y = pos[(size_t)(base + t) * 3 + 1];
        float z = pos[(size_t)(base + t) * 3 + 2];
        float sq = __fadd_rn(__fadd_rn(__fmul_rn(x, x), __fmul_rn(y, y)),
                             __fmul_rn(z, z));
        sp[t] = make_float4(x, y, z, sq);
    }
    __syncthreads();

    const int li = ((blockIdx.x & 3) << 8) + threadIdx.x;
    const float4 qi = sp[li];

    float s[KNN];
#pragma unroll
    for (int p = 0; p < KNN; ++p) s[p] = INFINITY;

    // pass 1: branch-free top-20 values
    for (int j0 = 0; j0 < NPG; j0 += 4) {
        float4 qa = sp[j0 + 0];
        float4 qb = sp[j0 + 1];
        float4 qc = sp[j0 + 2];
        float4 qd = sp[j0 + 3];
        float d0 = d2_exact(qi.x, qi.y, qi.z, qi.w, qa.x, qa.y, qa.z, qa.w);
        float d1 = d2_exact(qi.x, qi.y, qi.z, qi.w, qb.x, qb.y, qb.z, qb.w);
        float d2 = d2_exact(qi.x, qi.y, qi.z, qi.w, qc.x, qc.y, qc.z, qc.w);
        float d3 = d2_exact(qi.x, qi.y, qi.z, qi.w, qd.x, qd.y, qd.z, qd.w);
        d0 = (j0 + 0 == li) ? INFINITY : d0;
        d1 = (j0 + 1 == li) ? INFINITY : d1;
        d2 = (j0 + 2 == li) ? INFINITY : d2;
        d3 = (j0 + 3 == li) ? INFINITY : d3;
        float dd[4] = {d0, d1, d2, d3};
#pragma unroll
        for (int u = 0; u < 4; ++u) {
            const float d = dd[u];
#pragma unroll
            for (int p = KNN - 1; p >= 1; --p)
                s[p] = __builtin_amdgcn_fmed3f(s[p - 1], d, s[p]);
            s[0] = fminf(s[0], d);
        }
    }

    const float tau = s[KNN - 1];
    const int outbase = (base + li) * KNN;

    // pass 2: emit indices < tau; ties at tau ascending-j
    int cnt = 0;
    int tcnt = 0;
    int tie0 = 0, tie1 = 0, tie2 = 0, tie3 = 0;
    for (int j0 = 0; j0 < NPG; j0 += 4) {
        float4 qa = sp[j0 + 0];
        float4 qb = sp[j0 + 1];
        float4 qc = sp[j0 + 2];
        float4 qd = sp[j0 + 3];
        float dd[4];
        dd[0] = d2_exact(qi.x, qi.y, qi.z, qi.w, qa.x, qa.y, qa.z, qa.w);
        dd[1] = d2_exact(qi.x, qi.y, qi.z, qi.w, qb.x, qb.y, qb.z, qb.w);
        dd[2] = d2_exact(qi.x, qi.y, qi.z, qi.w, qc.x, qc.y, qc.z, qc.w);
        dd[3] = d2_exact(qi.x, qi.y, qi.z, qi.w, qd.x, qd.y, qd.z, qd.w);
#pragma unroll
        for (int u = 0; u < 4; ++u) {
            if (j0 + u == li) continue;
            const float d = dd[u];
            if (d < tau) {
                srcidx[outbase + cnt] = base + j0 + u;
                ++cnt;
            } else if (d == tau) {
                if (tcnt == 0) tie0 = j0 + u;
                else if (tcnt == 1) tie1 = j0 + u;
                else if (tcnt == 2) tie2 = j0 + u;
                else if (tcnt == 3) tie3 = j0 + u;
                ++tcnt;
            }
        }
    }
    const int need = KNN - cnt;
    if (need > 0) srcidx[outbase + cnt + 0] = base + tie0;
    if (need > 1) srcidx[outbase + cnt + 1] = base + tie1;
    if (need > 2) srcidx[outbase + cnt + 2] = base + tie2;
    if (need > 3) srcidx[outbase + cnt + 3] = base + tie3;
}

// ---------------------------------------------------------------------------
// embedding
// ---------------------------------------------------------------------------
__global__ __launch_bounds__(256) void embed_kernel(
    const float* __restrict__ pos,
    const float* __restrict__ w1, const float* __restrict__ b1,
    const float* __restrict__ w2, const float* __restrict__ b2,
    float* __restrict__ h) {
    const int i = blockIdx.x * 256 + threadIdx.x;
    if (i >= NTOT) return;
    const float x = pos[3 * (size_t)i + 0];
    const float y = pos[3 * (size_t)i + 1];
    const float z = pos[3 * (size_t)i + 2];

    float t[HD];
#pragma unroll
    for (int o = 0; o < HD; ++o)
        t[o] = silu_f(b1[o] + x * w1[0 * HD + o] + y * w1[1 * HD + o] + z * w1[2 * HD + o]);

    float r[HD];
#pragma unroll
    for (int o = 0; o < HD; ++o) r[o] = b2[o];
#pragma unroll
    for (int c = 0; c < HD; ++c) {
        const float a = t[c];
#pragma unroll
        for (int o = 0; o < HD; ++o) r[o] += a * w2[c * HD + o];
    }
    float4* hp = (float4*)(h + (size_t)i * HD);
    hp[0] = make_float4(r[0], r[1], r[2], r[3]);
    hp[1] = make_float4(r[4], r[5], r[6], r[7]);
    hp[2] = make_float4(r[8], r[9], r[10], r[11]);
    hp[3] = make_float4(r[12], r[13], r[14], r[15]);
}

// ---------------------------------------------------------------------------
// fused layer: edge MLP (1 thread/edge, float4 LDS weight reads) + in-block
// mean/max reduction + node MLP + residual, all in one kernel.
// ---------------------------------------------------------------------------
__global__ __launch_bounds__(TPB) void layer_kernel(
    const float* __restrict__ pos, const int* __restrict__ srcidx,
    const float* __restrict__ h_in, float* __restrict__ h_out,
    const float* __restrict__ ew1, const float* __restrict__ eb1,
    const float* __restrict__ ew2, const float* __restrict__ eb2,
    const float* __restrict__ ew3, const float* __restrict__ eb3,
    const float* __restrict__ nw1, const float* __restrict__ nb1,
    const float* __restrict__ nw2, const float* __restrict__ nb2) {
    __shared__ float w1s[37 * 32];
    __shared__ float b1s[32];
    __shared__ float w2s[32 * HD];
    __shared__ float b2s[HD];
    __shared__ float w3s[HD * HD];
    __shared__ float b3s[HD];
    __shared__ float n1s[48 * 32];
    __shared__ float nb1s[32];
    __shared__ float n2s[32 * HD];
    __shared__ float nb2s[HD];
    __shared__ float sm[TPB * HD];   // edge messages; aliased in node phase

    const int t = threadIdx.x;
    for (int u = t; u < 37 * 32; u += TPB) w1s[u] = ew1[u];
    for (int u = t; u < 32; u += TPB)      b1s[u] = eb1[u];
    for (int u = t; u < 32 * HD; u += TPB) w2s[u] = ew2[u];
    for (int u = t; u < HD; u += TPB)      b2s[u] = eb2[u];
    for (int u = t; u < HD * HD; u += TPB) w3s[u] = ew3[u];
    for (int u = t; u < HD; u += TPB)      b3s[u] = eb3[u];
    for (int u = t; u < 48 * 32; u += TPB) n1s[u] = nw1[u];
    for (int u = t; u < 32; u += TPB)      nb1s[u] = nb1[u];
    for (int u = t; u < 32 * HD; u += TPB) n2s[u] = nw2[u];
    for (int u = t; u < HD; u += TPB)      nb2s[u] = nb2[u];

    const int e = blockIdx.x * TPB + t;
    const int i = e / KNN;
    const int j = srcidx[e];

    const float pix = pos[3 * (size_t)i + 0];
    const float piy = pos[3 * (size_t)i + 1];
    const float piz = pos[3 * (size_t)i + 2];
    const float pjx = pos[3 * (size_t)j + 0];
    const float pjy = pos[3 * (size_t)j + 1];
    const float pjz = pos[3 * (size_t)j + 2];

    const float rx = pjx - pix, ry = pjy - piy, rz = pjz - piz;
    const float dist = sqrtf(rx * rx + ry * ry + rz * rz);
    const float rid  = 1.0f / (dist + 1e-8f);
    const float dirx = rx * rid, diry = ry * rid, dirz = rz * rid;
    const float ni  = sqrtf(pix * pix + piy * piy + piz * piz);
    const float rni = 1.0f / (ni + 1e-8f);
    const float nj  = sqrtf(pjx * pjx + pjy * pjy + pjz * pjz);
    const float rnj = 1.0f / (nj + 1e-8f);
    const float dotf = (pix * rni) * (pjx * rnj) + (piy * rni) * (pjy * rnj)
                     + (piz * rni) * (pjz * rnj);

    float hi[HD], hj[HD];
    {
        const float4* p = (const float4*)(h_in + (size_t)i * HD);
        float4 a = p[0], b = p[1], c = p[2], d = p[3];
        hi[0] = a.x; hi[1] = a.y; hi[2] = a.z; hi[3] = a.w;
        hi[4] = b.x; hi[5] = b.y; hi[6] = b.z; hi[7] = b.w;
        hi[8] = c.x; hi[9] = c.y; hi[10] = c.z; hi[11] = c.w;
        hi[12] = d.x; hi[13] = d.y; hi[14] = d.z; hi[15] = d.w;
    }
    {
        const float4* p = (const float4*)(h_in + (size_t)j * HD);
        float4 a = p[0], b = p[1], c = p[2], d = p[3];
        hj[0] = a.x; hj[1] = a.y; hj[2] = a.z; hj[3] = a.w;
        hj[4] = b.x; hj[5] = b.y; hj[6] = b.z; hj[7] = b.w;
        hj[8] = c.x; hj[9] = c.y; hj[10] = c.z; hj[11] = c.w;
        hj[12] = d.x; hj[13] = d.y; hj[14] = d.z; hj[15] = d.w;
    }

    __syncthreads();   // [S1] weights staged

    // --- edge MLP, all weight reads as float4 (b128 broadcasts) ---
    float t1[32];
#pragma unroll
    for (int og = 0; og < 8; ++og) {
        float4 bv = ((const float4*)b1s)[og];
        t1[4 * og + 0] = bv.x; t1[4 * og + 1] = bv.y;
        t1[4 * og + 2] = bv.z; t1[4 * og + 3] = bv.w;
    }
#pragma unroll
    for (int c = 0; c < HD; ++c) {
        const float a = hi[c], b = hj[c];
        const float4* wa = (const float4*)(w1s + c * 32);
        const float4* wb = (const float4*)(w1s + (HD + c) * 32);
#pragma unroll
        for (int og = 0; og < 8; ++og) {
            float4 u = wa[og], v = wb[og];
            t1[4 * og + 0] += a * u.x + b * v.x;
            t1[4 * og + 1] += a * u.y + b * v.y;
            t1[4 * og + 2] += a * u.z + b * v.z;
            t1[4 * og + 3] += a * u.w + b * v.w;
        }
    }
    {
        const float gg[5] = {dist, dirx, diry, dirz, dotf};
#pragma unroll
        for (int r = 0; r < 5; ++r) {
            const float a = gg[r];
            const float4* wg = (const float4*)(w1s + (32 + r) * 32);
#pragma unroll
            for (int og = 0; og < 8; ++og) {
                float4 u = wg[og];
                t1[4 * og + 0] += a * u.x;
                t1[4 * og + 1] += a * u.y;
                t1[4 * og + 2] += a * u.z;
                t1[4 * og + 3] += a * u.w;
            }
        }
    }
#pragma unroll
    for (int o = 0; o < 32; ++o) t1[o] = silu_f(t1[o]);

    float t2[HD];
#pragma unroll
    for (int og = 0; og < 4; ++og) {
        float4 bv = ((const float4*)b2s)[og];
        t2[4 * og + 0] = bv.x; t2[4 * og + 1] = bv.y;
        t2[4 * og + 2] = bv.z; t2[4 * og + 3] = bv.w;
    }
#pragma unroll
    for (int c = 0; c < 32; ++c) {
        const float a = t1[c];
        const float4* w = (const float4*)(w2s + c * HD);
#pragma unroll
        for (int og = 0; og < 4; ++og) {
            float4 u = w[og];
            t2[4 * og + 0] += a * u.x;
            t2[4 * og + 1] += a * u.y;
            t2[4 * og + 2] += a * u.z;
            t2[4 * og + 3] += a * u.w;
        }
    }
#pragma unroll
    for (int o = 0; o < HD; ++o) t2[o] = silu_f(t2[o]);

    // m = t2 @ ew3 + eb3 -> sm (float4 rows, 64B-aligned per thread)
    float4* smrow = (float4*)(sm + t * HD);
#pragma unroll
    for (int og = 0; og < 4; ++og) {
        float4 acc = ((const float4*)b3s)[og];
#pragma unroll
        for (int c = 0; c < HD; ++c) {
            const float a = t2[c];
            float4 u = ((const float4*)(w3s + c * HD))[og];
            acc.x += a * u.x; acc.y += a * u.y; acc.z += a * u.z; acc.w += a * u.w;
        }
        smrow[og] = acc;
    }

    __syncthreads();   // [S2] messages staged

    // --- reduction: thread (n,o) owns feature o of node n ---
    const int n = t >> 4;
    const int o = t & 15;
    float redsum = 0.0f, redmax = -INFINITY, hi_no = 0.0f;
    if (t < 256) {
#pragma unroll
        for (int k = 0; k < KNN; ++k) {
            float v = sm[(n * KNN + k) * HD + o];
            redsum += v;
            redmax = fmaxf(redmax, v);
        }
        hi_no = h_in[(size_t)blockIdx.x * 256 + t];
    }
    __syncthreads();   // [S3] sm reads complete; safe to alias

    float* hi_s = sm;          // [256]
    float* me_s = sm + 256;    // [256]
    float* mx_s = sm + 512;    // [256]
    float* u1_s = sm + 768;    // [16*40]

    if (t < 256) {
        hi_s[t] = hi_no;
        me_s[t] = redsum / 20.0f;
        mx_s[t] = redmax;
    }
    __syncthreads();   // [S4]

    if (t < 256) {
        float o0 = nb1s[o], o1 = nb1s[o + 16];
#pragma unroll
        for (int c = 0; c < HD; ++c) {
            const float hc = hi_s[n * HD + c];
            const float mc = me_s[n * HD + c];
            const float xc = mx_s[n * HD + c];
            o0 += hc * n1s[c * 32 + o]      + mc * n1s[(HD + c) * 32 + o]
                + xc * n1s[(2 * HD + c) * 32 + o];
            o1 += hc * n1s[c * 32 + o + 16] + mc * n1s[(HD + c) * 32 + o + 16]
                + xc * n1s[(2 * HD + c) * 32 + o + 16];
        }
        u1_s[n * 40 + o]      = silu_f(o0);
        u1_s[n * 40 + o + 16] = silu_f(o1);
    }
    __syncthreads();   // [S5]

    if (t < 256) {
        float acc = nb2s[o];
#pragma unroll
        for (int c = 0; c < 32; ++c) acc += u1_s[n * 40 + c] * n2s[c * HD + o];
        h_out[(size_t)blockIdx.x * 256 + t] = hi_no + acc;
    }
}

// ---------------------------------------------------------------------------
// output head
// ---------------------------------------------------------------------------
__global__ __launch_bounds__(256) void out_kernel(
    const float* __restrict__ h,
    const float* __restrict__ ow1, const float* __restrict__ ob1,
    const float* __restrict__ ow2, const float* __restrict__ ob2,
    const float* __restrict__ ow3, const float* __restrict__ ob3,
    float* __restrict__ out) {
    const int i = blockIdx.x * 256 + threadIdx.x;
    if (i >= NTOT) return;

    float hv[HD];
    {
        const float4* p = (const float4*)(h + (size_t)i * HD);
        float4 a = p[0], b = p[1], c = p[2], d = p[3];
        hv[0] = a.x; hv[1] = a.y; hv[2] = a.z; hv[3] = a.w;
        hv[4] = b.x; hv[5] = b.y; hv[6] = b.z; hv[7] = b.w;
        hv[8] = c.x; hv[9] = c.y; hv[10] = c.z; hv[11] = c.w;
        hv[12] = d.x; hv[13] = d.y; hv[14] = d.z; hv[15] = d.w;
    }

    float t1[HD];
#pragma unroll
    for (int o = 0; o < HD; ++o) t1[o] = ob1[o];
#pragma unroll
    for (int c = 0; c < HD; ++c) {
        const float a = hv[c];
#pragma unroll
        for (int o = 0; o < HD; ++o) t1[o] += a * ow1[c * HD + o];
    }
#pragma unroll
    for (int o = 0; o < HD; ++o) t1[o] = silu_f(t1[o]);

    float t2[8];
#pragma unroll
    for (int o = 0; o < 8; ++o) t2[o] = ob2[o];
#pragma unroll
    for (int c = 0; c < HD; ++c) {
        const float a = t1[c];
#pragma unroll
        for (int o = 0; o < 8; ++o) t2[o] += a * ow2[c * 8 + o];
    }
#pragma unroll
    for (int o = 0; o < 8; ++o) t2[o] = silu_f(t2[o]);

    float r0 = ob3[0], r1 = ob3[1], r2 = ob3[2];
#pragma unroll
    for (int c = 0; c < 8; ++c) {
        r0 += t2[c] * ow3[c * 3 + 0];
        r1 += t2[c] * ow3[c * 3 + 1];
        r2 += t2[c] * ow3[c * 3 + 2];
    }
    out[3 * (size_t)i + 0] = r0;
    out[3 * (size_t)i + 1] = r1;
    out[3 * (size_t)i + 2] = r2;
}

// ---------------------------------------------------------------------------
extern "C" void kernel_launch(void* const* d_in, const int* in_sizes, int n_in,
                              void* d_out, int out_size, void* d_ws, size_t ws_size,
                              hipStream_t stream) {
    const float* pos   = (const float*)d_in[0];
    const float* pe_w1 = (const float*)d_in[1];
    const float* pe_b1 = (const float*)d_in[2];
    const float* pe_w2 = (const float*)d_in[3];
    const float* pe_b2 = (const float*)d_in[4];
    const float* ew1   = (const float*)d_in[5];
    const float* eb1   = (const float*)d_in[6];
    const float* ew2   = (const float*)d_in[7];
    const float* eb2   = (const float*)d_in[8];
    const float* ew3   = (const float*)d_in[9];
    const float* eb3   = (const float*)d_in[10];
    const float* nw1   = (const float*)d_in[11];
    const float* nb1   = (const float*)d_in[12];
    const float* nw2   = (const float*)d_in[13];
    const float* nb2   = (const float*)d_in[14];
    const float* ow1   = (const float*)d_in[15];
    const float* ob1   = (const float*)d_in[16];
    const float* ow2   = (const float*)d_in[17];
    const float* ob2   = (const float*)d_in[18];
    const float* ow3   = (const float*)d_in[19];
    const float* ob3   = (const float*)d_in[20];

    char* ws = (char*)d_ws;
    int*   srcidx = (int*)ws;                                     // NTOT*KNN ints
    float* h0 = (float*)(ws + (size_t)NTOT * KNN * sizeof(int));
    float* h1 = h0 + (size_t)NTOT * HD;

    knn_kernel<<<NGRAPH * 4, 256, 0, stream>>>(pos, srcidx);
    embed_kernel<<<NTOT / 256, 256, 0, stream>>>(pos, pe_w1, pe_b1, pe_w2, pe_b2, h0);

    const int eblocks = (NTOT * KNN) / TPB;   // 4096
    for (int l = 0; l < 4; ++l) {
        const float* hin  = (l & 1) ? h1 : h0;
        float*       hout = (l & 1) ? h0 : h1;
        layer_kernel<<<eblocks, TPB, 0, stream>>>(
            pos, srcidx, hin, hout,
            ew1 + (size_t)l * 37 * 32, eb1 + (size_t)l * 32,
            ew2 + (size_t)l * 32 * 16, eb2 + (size_t)l * 16,
            ew3 + (size_t)l * 16 * 16, eb3 + (size_t)l * 16,
            nw1 + (size_t)l * 48 * 32, nb1 + (size_t)l * 32,
            nw2 + (size_t)l * 32 * 16, nb2 + (size_t)l * 16);
    }

    out_kernel<<<NTOT / 256, 256, 0, stream>>>(h0, ow1, ob1, ow2, ob2, ow3, ob3,
                                               (float*)d_out);
}

// Round 4
// 995.485 us; speedup vs baseline: 4.1479x; 1.2681x over previous
//
#include <hip/hip_runtime.h>
#include <math.h>

#define NPG    1024
#define KNN    20
#define NGRAPH 64
#define NTOT   (NGRAPH * NPG)   // 65536
#define HD     16
#define EPB    16               // nodes per layer-block
#define TPB    (EPB * KNN)      // 320 threads per layer-block
#define SMSTR  17               // padded LDS row stride (kills 2^k bank conflicts)

// ---------------------------------------------------------------------------
__device__ __forceinline__ float silu_f(float x) {
    float e = __expf(-x);
    return x * __fdividef(1.0f, 1.0f + e);
}

__device__ __forceinline__ float d2_exact(float xi, float yi, float zi, float sqi,
                                          float xj, float yj, float zj, float sqj) {
    float dot = __fadd_rn(__fadd_rn(__fmul_rn(xi, xj), __fmul_rn(yi, yj)),
                          __fmul_rn(zi, zj));
    return __fsub_rn(__fadd_rn(sqi, sqj), __fmul_rn(2.0f, dot));
}

// ---------------------------------------------------------------------------
// KNN (unchanged from R2)
// ---------------------------------------------------------------------------
__global__ __launch_bounds__(256) void knn_kernel(const float* __restrict__ pos,
                                                  int* __restrict__ srcidx) {
    __shared__ float4 sp[NPG];

    const int g    = blockIdx.x >> 2;
    const int base = g * NPG;

    for (int t = threadIdx.x; t < NPG; t += 256) {
        float x = pos[(size_t)(base + t) * 3 + 0];
        float y = pos[(size_t)(base + t) * 3 + 1];
        float z = pos[(size_t)(base + t) * 3 + 2];
        float sq = __fadd_rn(__fadd_rn(__fmul_rn(x, x), __fmul_rn(y, y)),
                             __fmul_rn(z, z));
        sp[t] = make_float4(x, y, z, sq);
    }
    __syncthreads();

    const int li = ((blockIdx.x & 3) << 8) + threadIdx.x;
    const float4 qi = sp[li];

    float s[KNN];
#pragma unroll
    for (int p = 0; p < KNN; ++p) s[p] = INFINITY;

    for (int j0 = 0; j0 < NPG; j0 += 4) {
        float4 qa = sp[j0 + 0];
        float4 qb = sp[j0 + 1];
        float4 qc = sp[j0 + 2];
        float4 qd = sp[j0 + 3];
        float d0 = d2_exact(qi.x, qi.y, qi.z, qi.w, qa.x, qa.y, qa.z, qa.w);
        float d1 = d2_exact(qi.x, qi.y, qi.z, qi.w, qb.x, qb.y, qb.z, qb.w);
        float d2 = d2_exact(qi.x, qi.y, qi.z, qi.w, qc.x, qc.y, qc.z, qc.w);
        float d3 = d2_exact(qi.x, qi.y, qi.z, qi.w, qd.x, qd.y, qd.z, qd.w);
        d0 = (j0 + 0 == li) ? INFINITY : d0;
        d1 = (j0 + 1 == li) ? INFINITY : d1;
        d2 = (j0 + 2 == li) ? INFINITY : d2;
        d3 = (j0 + 3 == li) ? INFINITY : d3;
        float dd[4] = {d0, d1, d2, d3};
#pragma unroll
        for (int u = 0; u < 4; ++u) {
            const float d = dd[u];
#pragma unroll
            for (int p = KNN - 1; p >= 1; --p)
                s[p] = __builtin_amdgcn_fmed3f(s[p - 1], d, s[p]);
            s[0] = fminf(s[0], d);
        }
    }

    const float tau = s[KNN - 1];
    const int outbase = (base + li) * KNN;

    int cnt = 0;
    int tcnt = 0;
    int tie0 = 0, tie1 = 0, tie2 = 0, tie3 = 0;
    for (int j0 = 0; j0 < NPG; j0 += 4) {
        float4 qa = sp[j0 + 0];
        float4 qb = sp[j0 + 1];
        float4 qc = sp[j0 + 2];
        float4 qd = sp[j0 + 3];
        float dd[4];
        dd[0] = d2_exact(qi.x, qi.y, qi.z, qi.w, qa.x, qa.y, qa.z, qa.w);
        dd[1] = d2_exact(qi.x, qi.y, qi.z, qi.w, qb.x, qb.y, qb.z, qb.w);
        dd[2] = d2_exact(qi.x, qi.y, qi.z, qi.w, qc.x, qc.y, qc.z, qc.w);
        dd[3] = d2_exact(qi.x, qi.y, qi.z, qi.w, qd.x, qd.y, qd.z, qd.w);
#pragma unroll
        for (int u = 0; u < 4; ++u) {
            if (j0 + u == li) continue;
            const float d = dd[u];
            if (d < tau) {
                srcidx[outbase + cnt] = base + j0 + u;
                ++cnt;
            } else if (d == tau) {
                if (tcnt == 0) tie0 = j0 + u;
                else if (tcnt == 1) tie1 = j0 + u;
                else if (tcnt == 2) tie2 = j0 + u;
                else if (tcnt == 3) tie3 = j0 + u;
                ++tcnt;
            }
        }
    }
    const int need = KNN - cnt;
    if (need > 0) srcidx[outbase + cnt + 0] = base + tie0;
    if (need > 1) srcidx[outbase + cnt + 1] = base + tie1;
    if (need > 2) srcidx[outbase + cnt + 2] = base + tie2;
    if (need > 3) srcidx[outbase + cnt + 3] = base + tie3;
}

// ---------------------------------------------------------------------------
// embedding (weights via uniform global indices -> SMEM)
// ---------------------------------------------------------------------------
__global__ __launch_bounds__(256) void embed_kernel(
    const float* __restrict__ pos,
    const float* __restrict__ w1, const float* __restrict__ b1,
    const float* __restrict__ w2, const float* __restrict__ b2,
    float* __restrict__ h) {
    const int i = blockIdx.x * 256 + threadIdx.x;
    if (i >= NTOT) return;
    const float x = pos[3 * (size_t)i + 0];
    const float y = pos[3 * (size_t)i + 1];
    const float z = pos[3 * (size_t)i + 2];

    float t[HD];
#pragma unroll
    for (int o = 0; o < HD; ++o)
        t[o] = silu_f(b1[o] + x * w1[0 * HD + o] + y * w1[1 * HD + o] + z * w1[2 * HD + o]);

    float r[HD];
#pragma unroll
    for (int o = 0; o < HD; ++o) r[o] = b2[o];
#pragma unroll
    for (int c = 0; c < HD; ++c) {
        const float a = t[c];
#pragma unroll
        for (int o = 0; o < HD; ++o) r[o] += a * w2[c * HD + o];
    }
    float4* hp = (float4*)(h + (size_t)i * HD);
    hp[0] = make_float4(r[0], r[1], r[2], r[3]);
    hp[1] = make_float4(r[4], r[5], r[6], r[7]);
    hp[2] = make_float4(r[8], r[9], r[10], r[11]);
    hp[3] = make_float4(r[12], r[13], r[14], r[15]);
}

// ---------------------------------------------------------------------------
// fused layer. Edge MLP weights read DIRECTLY from global with wave-uniform
// addresses (unrolled compile-time offsets) -> compiler scalar-loads (SMEM),
// freeing both the LDS and VALU pipes. LDS holds only the message tile
// (stride 17 -> conflict-free) and small node-phase staging.
// ---------------------------------------------------------------------------
__global__ __launch_bounds__(TPB) void layer_kernel(
    const float* __restrict__ pos, const int* __restrict__ srcidx,
    const float* __restrict__ h_in, float* __restrict__ h_out,
    const float* __restrict__ ew1, const float* __restrict__ eb1,
    const float* __restrict__ ew2, const float* __restrict__ eb2,
    const float* __restrict__ ew3, const float* __restrict__ eb3,
    const float* __restrict__ nw1, const float* __restrict__ nb1,
    const float* __restrict__ nw2, const float* __restrict__ nb2) {
    __shared__ float sm[TPB * SMSTR];   // 320*17*4 B = 21.76 KB

    const int t = threadIdx.x;
    const int e = blockIdx.x * TPB + t;
    const int i = e / KNN;
    const int j = srcidx[e];

    const float pix = pos[3 * (size_t)i + 0];
    const float piy = pos[3 * (size_t)i + 1];
    const float piz = pos[3 * (size_t)i + 2];
    const float pjx = pos[3 * (size_t)j + 0];
    const float pjy = pos[3 * (size_t)j + 1];
    const float pjz = pos[3 * (size_t)j + 2];

    const float rx = pjx - pix, ry = pjy - piy, rz = pjz - piz;
    const float dist = sqrtf(rx * rx + ry * ry + rz * rz);
    const float rid  = __fdividef(1.0f, dist + 1e-8f);
    const float dirx = rx * rid, diry = ry * rid, dirz = rz * rid;
    const float ni  = sqrtf(pix * pix + piy * piy + piz * piz);
    const float rni = __fdividef(1.0f, ni + 1e-8f);
    const float nj  = sqrtf(pjx * pjx + pjy * pjy + pjz * pjz);
    const float rnj = __fdividef(1.0f, nj + 1e-8f);
    const float dotf = (pix * rni) * (pjx * rnj) + (piy * rni) * (pjy * rnj)
                     + (piz * rni) * (pjz * rnj);

    float hi[HD], hj[HD];
    {
        const float4* p = (const float4*)(h_in + (size_t)i * HD);
        float4 a = p[0], b = p[1], c = p[2], d = p[3];
        hi[0] = a.x; hi[1] = a.y; hi[2] = a.z; hi[3] = a.w;
        hi[4] = b.x; hi[5] = b.y; hi[6] = b.z; hi[7] = b.w;
        hi[8] = c.x; hi[9] = c.y; hi[10] = c.z; hi[11] = c.w;
        hi[12] = d.x; hi[13] = d.y; hi[14] = d.z; hi[15] = d.w;
    }
    {
        const float4* p = (const float4*)(h_in + (size_t)j * HD);
        float4 a = p[0], b = p[1], c = p[2], d = p[3];
        hj[0] = a.x; hj[1] = a.y; hj[2] = a.z; hj[3] = a.w;
        hj[4] = b.x; hj[5] = b.y; hj[6] = b.z; hj[7] = b.w;
        hj[8] = c.x; hj[9] = c.y; hj[10] = c.z; hj[11] = c.w;
        hj[12] = d.x; hj[13] = d.y; hj[14] = d.z; hj[15] = d.w;
    }

    // --- edge MLP: weights via uniform global indices (scalar loads) ---
    float t1[32];
#pragma unroll
    for (int o = 0; o < 32; ++o) t1[o] = eb1[o];
#pragma unroll
    for (int c = 0; c < HD; ++c) {
        const float a = hi[c], b = hj[c];
#pragma unroll
        for (int o = 0; o < 32; ++o)
            t1[o] += a * ew1[c * 32 + o] + b * ew1[(HD + c) * 32 + o];
    }
#pragma unroll
    for (int o = 0; o < 32; ++o)
        t1[o] += dist * ew1[32 * 32 + o] + dirx * ew1[33 * 32 + o]
               + diry * ew1[34 * 32 + o] + dirz * ew1[35 * 32 + o]
               + dotf * ew1[36 * 32 + o];
#pragma unroll
    for (int o = 0; o < 32; ++o) t1[o] = silu_f(t1[o]);

    float t2[HD];
#pragma unroll
    for (int o = 0; o < HD; ++o) t2[o] = eb2[o];
#pragma unroll
    for (int c = 0; c < 32; ++c) {
        const float a = t1[c];
#pragma unroll
        for (int o = 0; o < HD; ++o) t2[o] += a * ew2[c * HD + o];
    }
#pragma unroll
    for (int o = 0; o < HD; ++o) t2[o] = silu_f(t2[o]);

    // m = t2 @ ew3 + eb3 -> sm (stride 17, conflict-free scalar writes)
#pragma unroll
    for (int o = 0; o < HD; ++o) {
        float mm = eb3[o];
#pragma unroll
        for (int c = 0; c < HD; ++c) mm += t2[c] * ew3[c * HD + o];
        sm[t * SMSTR + o] = mm;
    }

    __syncthreads();   // [S1] messages staged

    // --- reduction: thread (n,o) owns feature o of node n ---
    const int n = t >> 4;
    const int o = t & 15;
    float redsum = 0.0f, redmax = -INFINITY, hi_no = 0.0f;
    if (t < 256) {
#pragma unroll
        for (int k = 0; k < KNN; ++k) {
            float v = sm[(n * KNN + k) * SMSTR + o];
            redsum += v;
            redmax = fmaxf(redmax, v);
        }
        hi_no = h_in[(size_t)blockIdx.x * 256 + t];
    }
    __syncthreads();   // [S2] sm reads done; safe to alias

    float* hi_s = sm;          // [256]
    float* me_s = sm + 256;    // [256]
    float* mx_s = sm + 512;    // [256]
    float* u1_s = sm + 768;    // [16*40]

    if (t < 256) {
        hi_s[t] = hi_no;
        me_s[t] = redsum / 20.0f;
        mx_s[t] = redmax;
    }
    __syncthreads();   // [S3]

    if (t < 256) {
        float o0 = nb1[o], o1 = nb1[o + 16];
#pragma unroll
        for (int c = 0; c < HD; ++c) {
            const float hc = hi_s[n * HD + c];
            const float mc = me_s[n * HD + c];
            const float xc = mx_s[n * HD + c];
            o0 += hc * nw1[c * 32 + o]      + mc * nw1[(HD + c) * 32 + o]
                + xc * nw1[(2 * HD + c) * 32 + o];
            o1 += hc * nw1[c * 32 + o + 16] + mc * nw1[(HD + c) * 32 + o + 16]
                + xc * nw1[(2 * HD + c) * 32 + o + 16];
        }
        u1_s[n * 40 + o]      = silu_f(o0);
        u1_s[n * 40 + o + 16] = silu_f(o1);
    }
    __syncthreads();   // [S4]

    if (t < 256) {
        float acc = nb2[o];
#pragma unroll
        for (int c = 0; c < 32; ++c) acc += u1_s[n * 40 + c] * nw2[c * HD + o];
        h_out[(size_t)blockIdx.x * 256 + t] = hi_no + acc;
    }
}

// ---------------------------------------------------------------------------
// output head
// ---------------------------------------------------------------------------
__global__ __launch_bounds__(256) void out_kernel(
    const float* __restrict__ h,
    const float* __restrict__ ow1, const float* __restrict__ ob1,
    const float* __restrict__ ow2, const float* __restrict__ ob2,
    const float* __restrict__ ow3, const float* __restrict__ ob3,
    float* __restrict__ out) {
    const int i = blockIdx.x * 256 + threadIdx.x;
    if (i >= NTOT) return;

    float hv[HD];
    {
        const float4* p = (const float4*)(h + (size_t)i * HD);
        float4 a = p[0], b = p[1], c = p[2], d = p[3];
        hv[0] = a.x; hv[1] = a.y; hv[2] = a.z; hv[3] = a.w;
        hv[4] = b.x; hv[5] = b.y; hv[6] = b.z; hv[7] = b.w;
        hv[8] = c.x; hv[9] = c.y; hv[10] = c.z; hv[11] = c.w;
        hv[12] = d.x; hv[13] = d.y; hv[14] = d.z; hv[15] = d.w;
    }

    float t1[HD];
#pragma unroll
    for (int o = 0; o < HD; ++o) t1[o] = ob1[o];
#pragma unroll
    for (int c = 0; c < HD; ++c) {
        const float a = hv[c];
#pragma unroll
        for (int o = 0; o < HD; ++o) t1[o] += a * ow1[c * HD + o];
    }
#pragma unroll
    for (int o = 0; o < HD; ++o) t1[o] = silu_f(t1[o]);

    float t2[8];
#pragma unroll
    for (int o = 0; o < 8; ++o) t2[o] = ob2[o];
#pragma unroll
    for (int c = 0; c < HD; ++c) {
        const float a = t1[c];
#pragma unroll
        for (int o = 0; o < 8; ++o) t2[o] += a * ow2[c * 8 + o];
    }
#pragma unroll
    for (int o = 0; o < 8; ++o) t2[o] = silu_f(t2[o]);

    float r0 = ob3[0], r1 = ob3[1], r2 = ob3[2];
#pragma unroll
    for (int c = 0; c < 8; ++c) {
        r0 += t2[c] * ow3[c * 3 + 0];
        r1 += t2[c] * ow3[c * 3 + 1];
        r2 += t2[c] * ow3[c * 3 + 2];
    }
    out[3 * (size_t)i + 0] = r0;
    out[3 * (size_t)i + 1] = r1;
    out[3 * (size_t)i + 2] = r2;
}

// ---------------------------------------------------------------------------
extern "C" void kernel_launch(void* const* d_in, const int* in_sizes, int n_in,
                              void* d_out, int out_size, void* d_ws, size_t ws_size,
                              hipStream_t stream) {
    const float* pos   = (const float*)d_in[0];
    const float* pe_w1 = (const float*)d_in[1];
    const float* pe_b1 = (const float*)d_in[2];
    const float* pe_w2 = (const float*)d_in[3];
    const float* pe_b2 = (const float*)d_in[4];
    const float* ew1   = (const float*)d_in[5];
    const float* eb1   = (const float*)d_in[6];
    const float* ew2   = (const float*)d_in[7];
    const float* eb2   = (const float*)d_in[8];
    const float* ew3   = (const float*)d_in[9];
    const float* eb3   = (const float*)d_in[10];
    const float* nw1   = (const float*)d_in[11];
    const float* nb1   = (const float*)d_in[12];
    const float* nw2   = (const float*)d_in[13];
    const float* nb2   = (const float*)d_in[14];
    const float* ow1   = (const float*)d_in[15];
    const float* ob1   = (const float*)d_in[16];
    const float* ow2   = (const float*)d_in[17];
    const float* ob2   = (const float*)d_in[18];
    const float* ow3   = (const float*)d_in[19];
    const float* ob3   = (const float*)d_in[20];

    char* ws = (char*)d_ws;
    int*   srcidx = (int*)ws;                                     // NTOT*KNN ints
    float* h0 = (float*)(ws + (size_t)NTOT * KNN * sizeof(int));
    float* h1 = h0 + (size_t)NTOT * HD;

    knn_kernel<<<NGRAPH * 4, 256, 0, stream>>>(pos, srcidx);
    embed_kernel<<<NTOT / 256, 256, 0, stream>>>(pos, pe_w1, pe_b1, pe_w2, pe_b2, h0);

    const int eblocks = (NTOT * KNN) / TPB;   // 4096
    for (int l = 0; l < 4; ++l) {
        const float* hin  = (l & 1) ? h1 : h0;
        float*       hout = (l & 1) ? h0 : h1;
        layer_kernel<<<eblocks, TPB, 0, stream>>>(
            pos, srcidx, hin, hout,
            ew1 + (size_t)l * 37 * 32, eb1 + (size_t)l * 32,
            ew2 + (size_t)l * 32 * 16, eb2 + (size_t)l * 16,
            ew3 + (size_t)l * 16 * 16, eb3 + (size_t)l * 16,
            nw1 + (size_t)l * 48 * 32, nb1 + (size_t)l * 32,
            nw2 + (size_t)l * 32 * 16, nb2 + (size_t)l * 16);
    }

    out_kernel<<<NTOT / 256, 256, 0, stream>>>(h0, ow1, ob1, ow2, ob2, ow3, ob3,
                                               (float*)d_out);
}